// Round 6
// baseline (278.498 us; speedup 1.0000x reference)
//
#include <hip/hip_runtime.h>
#include <math.h>

#define IN_DIM 128
#define HID    128
#define NN     100000
#define BM     64                        // edges per tile
#define GRID_BLOCKS 768                  // 3 blocks/CU * 256 CU (persistent)
#define WPACK_BYTES (64 * 64 * 16)       // 64 frags x 64 lanes x 16B = 64 KB
#define WPACK_OFF   64
#define ZBF_OFF     (WPACK_OFF + WPACK_BYTES + 192)          // 65792, 256-aligned
#define ZBF_BYTES   (NN * IN_DIM * 2)                        // 25.6 MB

typedef __attribute__((ext_vector_type(8))) __bf16 bf16x8;
typedef __attribute__((ext_vector_type(4))) float  f32x4;

__device__ __forceinline__ unsigned pk2bf(float a, float b) {
    union { __bf16 h[2]; unsigned u; } r;
    r.h[0] = (__bf16)a; r.h[1] = (__bf16)b;   // v_cvt_pk_bf16_f32
    return r.u;
}

// dtype probe + W1 -> per-lane bf16 MFMA B-fragment pack
__global__ void prep(const float* __restrict__ W1,
                     const unsigned* __restrict__ ei,
                     uint4* __restrict__ wpack,
                     int* __restrict__ flag, int do_pack) {
    const int t = threadIdx.x;
    if (t < 64) {
        unsigned v = ei[2 * t + 1];
        unsigned long long b = __ballot(v != 0u);
        if (t == 0) flag[0] = (b == 0ull) ? 1 : 0;
    }
    if (!do_pack) return;
    const int lane = t & 63;
    #pragma unroll
    for (int fi = 0; fi < 16; ++fi) {
        const int frag = (t >> 6) + fi * 4;
        const int kc = frag >> 3, jsg = frag & 7;
        const int k0 = kc * 32 + (lane >> 4) * 8;
        const int j  = jsg * 16 + (lane & 15);
        unsigned wv[4];
        #pragma unroll
        for (int p = 0; p < 4; ++p)
            wv[p] = pk2bf(W1[(k0 + 2 * p) * HID + j], W1[(k0 + 2 * p + 1) * HID + j]);
        wpack[frag * 64 + lane] = make_uint4(wv[0], wv[1], wv[2], wv[3]);
    }
}

// z fp32 -> bf16 (row-major, 32 uint2 per node row)
__global__ void zconv(const float4* __restrict__ z4, uint2* __restrict__ zbf, int n4) {
    for (int i = blockIdx.x * blockDim.x + threadIdx.x; i < n4; i += gridDim.x * blockDim.x) {
        const float4 v = z4[i];
        zbf[i] = make_uint2(pk2bf(v.x, v.y), pk2bf(v.z, v.w));
    }
}

// ---------------- fast path: bf16 z, prefetch pipeline ----------------
__global__ __launch_bounds__(256, 3)
void lp_main_bf(const uint2* __restrict__ zbf,
                const int* __restrict__ ei32,
                const float* __restrict__ b1,
                const float* __restrict__ W2,
                const float* __restrict__ b2,
                float* __restrict__ out,
                const int* __restrict__ flag,
                const uint4* __restrict__ wpack,
                int E, int ntiles)
{
    __shared__ uint4 ldsA_[BM * 512 / 16];      // 32 KB, XOR-swizzled rows
    __shared__ float part[4][BM];
    char* ldsc = (char*)ldsA_;

    const int t    = threadIdx.x;
    const int lane = t & 63;
    const int w    = t >> 6;
    const int use64 = flag[0];

    uint4 Bf[8][2];
    #pragma unroll
    for (int kc = 0; kc < 8; ++kc)
        #pragma unroll
        for (int js = 0; js < 2; ++js)
            Bf[kc][js] = wpack[(kc * 8 + (w * 2 + js)) * 64 + lane];

    const int e_r = lane & 15;
    const int q   = lane >> 4;
    const int m16 = q * 16;
    const float b1v0 = b1[w * 32 + e_r], b1v1 = b1[w * 32 + 16 + e_r];
    const float w2v0 = W2[w * 32 + e_r], w2v1 = W2[w * 32 + 16 + e_r];
    const float b2v  = b2[0];
    const int half = (lane < 32) ? 0 : 1;    // src vs dst gather role
    const int koff = lane & 31;              // uint2 slot within node row

#define GATHER(TILE, PF)                                                    \
    {                                                                       \
        const int e0g = (TILE) * BM;                                        \
        _Pragma("unroll")                                                   \
        for (int i = 0; i < 16; ++i) {                                      \
            const int el = i * 4 + w;                                       \
            int e = e0g + el; if (e > E - 1) e = E - 1;                     \
            const int word = half ? (E + e) : e;                            \
            int node = ei32[(long long)word << use64];                      \
            node = min(max(node, 0), NN - 1);                               \
            PF[i] = zbf[node * 32 + koff];                                  \
        }                                                                   \
    }

    int tile = blockIdx.x;
    if (tile >= ntiles) return;
    uint2 pf[16];
    GATHER(tile, pf);

    for (; tile < ntiles; tile += gridDim.x) {
        // keep Bf register-resident across the loop (R5: pre-loop pin failed;
        // VGPR=76 proved remat inside loop). In-loop empty asm = hard liveness.
        #pragma unroll
        for (int kc = 0; kc < 8; ++kc)
            #pragma unroll
            for (int js = 0; js < 2; ++js)
                asm volatile("" : "+v"(Bf[kc][js].x), "+v"(Bf[kc][js].y),
                                  "+v"(Bf[kc][js].z), "+v"(Bf[kc][js].w));

        // write prefetched A-tile (waits on its vmcnt automatically)
        #pragma unroll
        for (int i = 0; i < 16; ++i) {
            const int el = i * 4 + w;
            const int byte = el * 512 + ((lane * 8) ^ ((el & 7) << 4));
            *reinterpret_cast<uint2*>(ldsc + byte) = pf[i];
        }
        // issue next tile's gather; returns land during the K-loop below
        const int next = tile + gridDim.x;
        if (next < ntiles) GATHER(next, pf);
        __syncthreads();

        // ---- K loop: 32 ds_read_b128 + 64 MFMA per wave ----
        f32x4 acc[4][2] = {};
        #pragma unroll
        for (int kc = 0; kc < 8; ++kc) {
            #pragma unroll
            for (int es = 0; es < 4; ++es) {
                const int row  = es * 16 + e_r;
                const int byte = row * 512 + ((kc * 64 + m16) ^ ((row & 7) << 4));
                const bf16x8 a = *reinterpret_cast<const bf16x8*>(ldsc + byte);
                acc[es][0] = __builtin_amdgcn_mfma_f32_16x16x32_bf16(
                    a, __builtin_bit_cast(bf16x8, Bf[kc][0]), acc[es][0], 0, 0, 0);
                acc[es][1] = __builtin_amdgcn_mfma_f32_16x16x32_bf16(
                    a, __builtin_bit_cast(bf16x8, Bf[kc][1]), acc[es][1], 0, 0, 0);
            }
        }

        // ---- fused layer 2: relu(acc+b1).W2, 15-shuffle distribute-reduce ----
        float v16[16];
        #pragma unroll
        for (int es = 0; es < 4; ++es)
            #pragma unroll
            for (int reg = 0; reg < 4; ++reg)
                v16[es * 4 + reg] = fmaxf(acc[es][0][reg] + b1v0, 0.f) * w2v0
                                  + fmaxf(acc[es][1][reg] + b1v1, 0.f) * w2v1;
        #pragma unroll
        for (int rnd = 0; rnd < 4; ++rnd) {
            const int o = 1 << rnd;
            const int hl = 8 >> rnd;
            #pragma unroll
            for (int i = 0; i < hl; ++i) {
                const float a = v16[i], b = v16[i + hl];
                const float s = (lane & o) ? a : b;
                const float r = __shfl_xor(s, o);
                v16[i] = ((lane & o) ? b : a) + r;
            }
        }
        {
            const int l4  = lane & 15;
            const int idx = ((l4 & 1) << 3) | ((l4 & 2) << 1) | ((l4 & 4) >> 1) | ((l4 & 8) >> 3);
            const int edge = (idx >> 2) * 16 + q * 4 + (idx & 3);
            part[w][edge] = v16[0];
        }
        __syncthreads();

        if (t < BM) {
            const int e = tile * BM + t;
            if (e < E) {
                const float s = part[0][t] + part[1][t] + part[2][t] + part[3][t] + b2v;
                out[e] = 1.f / (1.f + expf(-s));
            }
        }
        // wave0's part reads happen before the next iteration's first barrier,
        // which fences them from part(t+1) writes; A(t+1) ds_writes only
        // overwrite data all waves finished reading before the barrier above.
    }
#undef GATHER
}

// ---------------- fallback path (R5 kernel, fp32 z gather) ----------------
__global__ __launch_bounds__(256, 3)
void lp_main(const float* __restrict__ z,
             const int* __restrict__ ei32,
             const float* __restrict__ W1,
             const float* __restrict__ b1,
             const float* __restrict__ W2,
             const float* __restrict__ b2,
             float* __restrict__ out,
             const int* __restrict__ flag,
             const uint4* __restrict__ wpack,
             int use_ws, int E, int ntiles)
{
    __shared__ uint4 ldsA_[BM * 512 / 16];
    __shared__ float part[4][BM];
    char* ldsc = (char*)ldsA_;

    const int t    = threadIdx.x;
    const int lane = t & 63;
    const int w    = t >> 6;
    const int use64 = flag[0];

    uint4 Bf[8][2];
    if (use_ws) {
        #pragma unroll
        for (int kc = 0; kc < 8; ++kc)
            #pragma unroll
            for (int js = 0; js < 2; ++js)
                Bf[kc][js] = wpack[(kc * 8 + (w * 2 + js)) * 64 + lane];
    } else {
        #pragma unroll
        for (int kc = 0; kc < 8; ++kc)
            #pragma unroll
            for (int js = 0; js < 2; ++js) {
                const int k0 = kc * 32 + (lane >> 4) * 8;
                const int j  = (w * 2 + js) * 16 + (lane & 15);
                unsigned wv[4];
                #pragma unroll
                for (int p = 0; p < 4; ++p)
                    wv[p] = pk2bf(W1[(k0 + 2 * p) * HID + j],
                                  W1[(k0 + 2 * p + 1) * HID + j]);
                Bf[kc][js] = make_uint4(wv[0], wv[1], wv[2], wv[3]);
            }
    }

    const int e_r = lane & 15;
    const int q   = lane >> 4;
    const int m16 = q * 16;
    const float b1v0 = b1[w * 32 + e_r], b1v1 = b1[w * 32 + 16 + e_r];
    const float w2v0 = W2[w * 32 + e_r], w2v1 = W2[w * 32 + 16 + e_r];
    const float b2v  = b2[0];

    for (int tile = blockIdx.x; tile < ntiles; tile += gridDim.x) {
        const int e0 = tile * BM;
        #pragma unroll
        for (int kc = 0; kc < 8; ++kc)
            #pragma unroll
            for (int js = 0; js < 2; ++js)
                asm volatile("" : "+v"(Bf[kc][js].x), "+v"(Bf[kc][js].y),
                                  "+v"(Bf[kc][js].z), "+v"(Bf[kc][js].w));

        #pragma unroll 8
        for (int i = 0; i < 16; ++i) {
            const int el = i * 4 + w;
            int e = e0 + el; if (e > E - 1) e = E - 1;
            const int word = (lane < 32) ? e : (E + e);
            int node = ei32[(long long)word << use64];
            node = min(max(node, 0), NN - 1);
            const float4 v = *reinterpret_cast<const float4*>(
                &z[node * IN_DIM + (lane & 31) * 4]);
            const int byte = el * 512 + ((lane * 8) ^ ((el & 7) << 4));
            *reinterpret_cast<uint2*>(ldsc + byte) =
                make_uint2(pk2bf(v.x, v.y), pk2bf(v.z, v.w));
        }
        __syncthreads();

        f32x4 acc[4][2] = {};
        #pragma unroll
        for (int kc = 0; kc < 8; ++kc) {
            #pragma unroll
            for (int es = 0; es < 4; ++es) {
                const int row  = es * 16 + e_r;
                const int byte = row * 512 + ((kc * 64 + m16) ^ ((row & 7) << 4));
                const bf16x8 a = *reinterpret_cast<const bf16x8*>(ldsc + byte);
                acc[es][0] = __builtin_amdgcn_mfma_f32_16x16x32_bf16(
                    a, __builtin_bit_cast(bf16x8, Bf[kc][0]), acc[es][0], 0, 0, 0);
                acc[es][1] = __builtin_amdgcn_mfma_f32_16x16x32_bf16(
                    a, __builtin_bit_cast(bf16x8, Bf[kc][1]), acc[es][1], 0, 0, 0);
            }
        }

        float v16[16];
        #pragma unroll
        for (int es = 0; es < 4; ++es)
            #pragma unroll
            for (int reg = 0; reg < 4; ++reg)
                v16[es * 4 + reg] = fmaxf(acc[es][0][reg] + b1v0, 0.f) * w2v0
                                  + fmaxf(acc[es][1][reg] + b1v1, 0.f) * w2v1;
        #pragma unroll
        for (int rnd = 0; rnd < 4; ++rnd) {
            const int o = 1 << rnd;
            const int hl = 8 >> rnd;
            #pragma unroll
            for (int i = 0; i < hl; ++i) {
                const float a = v16[i], b = v16[i + hl];
                const float s = (lane & o) ? a : b;
                const float r = __shfl_xor(s, o);
                v16[i] = ((lane & o) ? b : a) + r;
            }
        }
        {
            const int l4  = lane & 15;
            const int idx = ((l4 & 1) << 3) | ((l4 & 2) << 1) | ((l4 & 4) >> 1) | ((l4 & 8) >> 3);
            const int edge = (idx >> 2) * 16 + q * 4 + (idx & 3);
            part[w][edge] = v16[0];
        }
        __syncthreads();

        if (t < BM) {
            const int e = e0 + t;
            if (e < E) {
                const float s = part[0][t] + part[1][t] + part[2][t] + part[3][t] + b2v;
                out[e] = 1.f / (1.f + expf(-s));
            }
        }
    }
}

extern "C" void kernel_launch(void* const* d_in, const int* in_sizes, int n_in,
                              void* d_out, int out_size, void* d_ws, size_t ws_size,
                              hipStream_t stream) {
    const float* z  = (const float*)d_in[0];
    const void*  ei = d_in[1];
    const float* W1 = (const float*)d_in[2];
    const float* b1 = (const float*)d_in[3];
    const float* W2 = (const float*)d_in[4];
    const float* b2 = (const float*)d_in[5];
    float* out = (float*)d_out;
    int*   flag  = (int*)d_ws;
    uint4* wpack = (uint4*)((char*)d_ws + WPACK_OFF);
    uint2* zbf   = (uint2*)((char*)d_ws + ZBF_OFF);

    const int E = in_sizes[1] / 2;
    const int use_ws  = (ws_size >= (size_t)(WPACK_OFF + WPACK_BYTES)) ? 1 : 0;
    const int use_zbf = (ws_size >= (size_t)(ZBF_OFF + ZBF_BYTES)) ? 1 : 0;

    hipLaunchKernelGGL(prep, dim3(1), dim3(256), 0, stream,
                       W1, (const unsigned*)ei, wpack, flag, use_ws);

    const int ntiles = (E + BM - 1) / BM;
    const int grid = (ntiles < GRID_BLOCKS) ? ntiles : GRID_BLOCKS;

    if (use_zbf) {
        const int n4 = NN * IN_DIM / 4;
        hipLaunchKernelGGL(zconv, dim3(2048), dim3(256), 0, stream,
                           (const float4*)z, zbf, n4);
        hipLaunchKernelGGL(lp_main_bf, dim3(grid), dim3(256), 0, stream,
                           zbf, (const int*)ei, b1, W2, b2, out, flag, wpack, E, ntiles);
    } else {
        hipLaunchKernelGGL(lp_main, dim3(grid), dim3(256), 0, stream,
                           z, (const int*)ei, W1, b1, W2, b2, out, flag, wpack,
                           use_ws, E, ntiles);
    }
}

// Round 7
// 141.446 us; speedup vs baseline: 1.9689x; 1.9689x over previous
//
#include <hip/hip_runtime.h>
#include <math.h>

#define IN_DIM 128
#define HID    128
#define NN     100000
#define BM     64                        // edges per tile
#define GRID_BLOCKS 1024                 // 4 blocks/CU (LDS 33KB x4 = 132KB < 160KB)
#define WPACK_BYTES (64 * 64 * 16)       // 64 frags x 64 lanes x 16B = 64 KB
#define WPACK_OFF   64
#define ZBF_OFF     (WPACK_OFF + WPACK_BYTES + 192)          // 256-aligned
#define ZBF_BYTES   (NN * IN_DIM * 2)                        // 25.6 MB

typedef __attribute__((ext_vector_type(8))) __bf16 bf16x8;
typedef __attribute__((ext_vector_type(4))) float  f32x4;

#define AS1(p) ((const __attribute__((address_space(1))) void*)(p))
#define AS3(p) ((__attribute__((address_space(3))) void*)(p))

__device__ __forceinline__ unsigned pk2bf(float a, float b) {
    union { __bf16 h[2]; unsigned u; } r;
    r.h[0] = (__bf16)a; r.h[1] = (__bf16)b;   // v_cvt_pk_bf16_f32
    return r.u;
}

// dtype probe + W1 -> per-lane bf16 MFMA B-fragment pack
__global__ void prep(const float* __restrict__ W1,
                     const unsigned* __restrict__ ei,
                     uint4* __restrict__ wpack,
                     int* __restrict__ flag, int do_pack) {
    const int t = threadIdx.x;
    if (t < 64) {
        unsigned v = ei[2 * t + 1];
        unsigned long long b = __ballot(v != 0u);
        if (t == 0) flag[0] = (b == 0ull) ? 1 : 0;
    }
    if (!do_pack) return;
    const int lane = t & 63;
    #pragma unroll
    for (int fi = 0; fi < 16; ++fi) {
        const int frag = (t >> 6) + fi * 4;
        const int kc = frag >> 3, jsg = frag & 7;
        const int k0 = kc * 32 + (lane >> 4) * 8;
        const int j  = jsg * 16 + (lane & 15);
        unsigned wv[4];
        #pragma unroll
        for (int p = 0; p < 4; ++p)
            wv[p] = pk2bf(W1[(k0 + 2 * p) * HID + j], W1[(k0 + 2 * p + 1) * HID + j]);
        wpack[frag * 64 + lane] = make_uint4(wv[0], wv[1], wv[2], wv[3]);
    }
}

// z fp32 -> bf16 row-major (256 B per node row)
__global__ void zconv(const float4* __restrict__ z4, uint4* __restrict__ zbf4, int n8) {
    for (int i = blockIdx.x * blockDim.x + threadIdx.x; i < n8; i += gridDim.x * blockDim.x) {
        const float4 a = z4[2 * i], b = z4[2 * i + 1];
        zbf4[i] = make_uint4(pk2bf(a.x, a.y), pk2bf(a.z, a.w),
                             pk2bf(b.x, b.y), pk2bf(b.z, b.w));
    }
}

// ---------------- fast path: bf16 z, global_load_lds staging ----------------
__global__ __launch_bounds__(256, 4)
void lp_main_bf(const char* __restrict__ zbf,
                const int* __restrict__ ei32,
                const float* __restrict__ b1,
                const float* __restrict__ W2,
                const float* __restrict__ b2,
                float* __restrict__ out,
                const int* __restrict__ flag,
                const uint4* __restrict__ wpack,
                int E, int ntiles)
{
    // A-tile: 64 rows x 512B (row = [src bf16 x128 | dst bf16 x128]),
    // XOR-swizzled byte ^= (row&7)<<4 — applied on the GLOBAL SOURCE side
    // (global_load_lds dest must be lane-linear, m104/m173).
    __shared__ uint4 ldsA_[BM * 512 / 16];      // 32 KB
    __shared__ float part[4][BM];
    char* ldsc = (char*)ldsA_;

    const int t    = threadIdx.x;
    const int lane = t & 63;
    const int w    = t >> 6;
    const int use64 = flag[0];

    const int e_r = lane & 15;
    const int q   = lane >> 4;
    const int m16 = q * 16;
    const float b1v0 = b1[w * 32 + e_r], b1v1 = b1[w * 32 + 16 + e_r];
    const float w2v0 = W2[w * 32 + e_r], w2v1 = W2[w * 32 + 16 + e_r];
    const float b2v  = b2[0];

    for (int tile = blockIdx.x; tile < ntiles; tile += gridDim.x) {
        const int e0 = tile * BM;

        // ---- stage A-tile: 8 async 1KB loads per wave (2 edges each) ----
        // lane -> LDS byte el0*512 + lane*16; source granule (lane&31)^(el&7)
        // of edge el = el0 + (lane>>5); half (src/dst) = bit4 of lane.
        #pragma unroll
        for (int i = 0; i < 8; ++i) {
            const int el0 = w * 16 + 2 * i;
            const int el  = el0 + (lane >> 5);
            int e = e0 + el; if (e > E - 1) e = E - 1;
            const int word = ((lane >> 4) & 1) ? (E + e) : e;
            int node = ei32[(long long)word << use64];
            node = min(max(node, 0), NN - 1);
            const int lp16 = (lane & 31) ^ (el & 7);     // swizzled 16B granule
            const char* g = zbf + (node << 8) + ((lp16 & 15) << 4);
            __builtin_amdgcn_global_load_lds(AS1(g), AS3(ldsc + el0 * 512), 16, 0, 0);
        }
        __syncthreads();   // compiler emits vmcnt(0) drain before s_barrier

        // ---- K loop: 32 ds_read_b128 + 64 MFMA per wave ----
        f32x4 acc[4][2] = {};
        #pragma unroll
        for (int kc = 0; kc < 8; ++kc) {
            #pragma unroll
            for (int es = 0; es < 4; ++es) {
                const int row  = es * 16 + e_r;
                const int byte = row * 512 + ((kc * 64 + m16) ^ ((row & 7) << 4));
                const bf16x8 a = *reinterpret_cast<const bf16x8*>(ldsc + byte);
                const uint4 bf0 = wpack[(kc * 8 + w * 2 + 0) * 64 + lane];
                const uint4 bf1 = wpack[(kc * 8 + w * 2 + 1) * 64 + lane];
                acc[es][0] = __builtin_amdgcn_mfma_f32_16x16x32_bf16(
                    a, __builtin_bit_cast(bf16x8, bf0), acc[es][0], 0, 0, 0);
                acc[es][1] = __builtin_amdgcn_mfma_f32_16x16x32_bf16(
                    a, __builtin_bit_cast(bf16x8, bf1), acc[es][1], 0, 0, 0);
            }
        }

        // ---- fused layer 2: relu(acc+b1).W2, 15-shuffle distribute-reduce ----
        float v16[16];
        #pragma unroll
        for (int es = 0; es < 4; ++es)
            #pragma unroll
            for (int reg = 0; reg < 4; ++reg)
                v16[es * 4 + reg] = fmaxf(acc[es][0][reg] + b1v0, 0.f) * w2v0
                                  + fmaxf(acc[es][1][reg] + b1v1, 0.f) * w2v1;
        #pragma unroll
        for (int rnd = 0; rnd < 4; ++rnd) {
            const int o = 1 << rnd;
            const int hl = 8 >> rnd;
            #pragma unroll
            for (int i = 0; i < hl; ++i) {
                const float a = v16[i], b = v16[i + hl];
                const float s = (lane & o) ? a : b;
                const float r = __shfl_xor(s, o);
                v16[i] = ((lane & o) ? b : a) + r;
            }
        }
        {
            const int l4  = lane & 15;
            const int idx = ((l4 & 1) << 3) | ((l4 & 2) << 1) | ((l4 & 4) >> 1) | ((l4 & 8) >> 3);
            const int edge = (idx >> 2) * 16 + q * 4 + (idx & 3);
            part[w][edge] = v16[0];
        }
        __syncthreads();

        if (t < BM) {
            const int e = e0 + t;
            if (e < E) {
                const float s = part[0][t] + part[1][t] + part[2][t] + part[3][t] + b2v;
                out[e] = 1.f / (1.f + expf(-s));
            }
        }
    }
}

// ---------------- fallback path (R5 kernel, fp32 z gather, no pins) ----------------
__global__ __launch_bounds__(256, 3)
void lp_main(const float* __restrict__ z,
             const int* __restrict__ ei32,
             const float* __restrict__ W1,
             const float* __restrict__ b1,
             const float* __restrict__ W2,
             const float* __restrict__ b2,
             float* __restrict__ out,
             const int* __restrict__ flag,
             const uint4* __restrict__ wpack,
             int use_ws, int E, int ntiles)
{
    __shared__ uint4 ldsA_[BM * 512 / 16];
    __shared__ float part[4][BM];
    char* ldsc = (char*)ldsA_;

    const int t    = threadIdx.x;
    const int lane = t & 63;
    const int w    = t >> 6;
    const int use64 = flag[0];

    uint4 Bf[8][2];
    if (use_ws) {
        #pragma unroll
        for (int kc = 0; kc < 8; ++kc)
            #pragma unroll
            for (int js = 0; js < 2; ++js)
                Bf[kc][js] = wpack[(kc * 8 + (w * 2 + js)) * 64 + lane];
    } else {
        #pragma unroll
        for (int kc = 0; kc < 8; ++kc)
            #pragma unroll
            for (int js = 0; js < 2; ++js) {
                const int k0 = kc * 32 + (lane >> 4) * 8;
                const int j  = (w * 2 + js) * 16 + (lane & 15);
                unsigned wv[4];
                #pragma unroll
                for (int p = 0; p < 4; ++p)
                    wv[p] = pk2bf(W1[(k0 + 2 * p) * HID + j],
                                  W1[(k0 + 2 * p + 1) * HID + j]);
                Bf[kc][js] = make_uint4(wv[0], wv[1], wv[2], wv[3]);
            }
    }

    const int e_r = lane & 15;
    const int q   = lane >> 4;
    const int m16 = q * 16;
    const float b1v0 = b1[w * 32 + e_r], b1v1 = b1[w * 32 + 16 + e_r];
    const float w2v0 = W2[w * 32 + e_r], w2v1 = W2[w * 32 + 16 + e_r];
    const float b2v  = b2[0];

    for (int tile = blockIdx.x; tile < ntiles; tile += gridDim.x) {
        const int e0 = tile * BM;
        #pragma unroll 8
        for (int i = 0; i < 16; ++i) {
            const int el = i * 4 + w;
            int e = e0 + el; if (e > E - 1) e = E - 1;
            const int word = (lane < 32) ? e : (E + e);
            int node = ei32[(long long)word << use64];
            node = min(max(node, 0), NN - 1);
            const float4 v = *reinterpret_cast<const float4*>(
                &z[node * IN_DIM + (lane & 31) * 4]);
            const int byte = el * 512 + ((lane * 8) ^ ((el & 7) << 4));
            *reinterpret_cast<uint2*>(ldsc + byte) =
                make_uint2(pk2bf(v.x, v.y), pk2bf(v.z, v.w));
        }
        __syncthreads();

        f32x4 acc[4][2] = {};
        #pragma unroll
        for (int kc = 0; kc < 8; ++kc) {
            #pragma unroll
            for (int es = 0; es < 4; ++es) {
                const int row  = es * 16 + e_r;
                const int byte = row * 512 + ((kc * 64 + m16) ^ ((row & 7) << 4));
                const bf16x8 a = *reinterpret_cast<const bf16x8*>(ldsc + byte);
                acc[es][0] = __builtin_amdgcn_mfma_f32_16x16x32_bf16(
                    a, __builtin_bit_cast(bf16x8, Bf[kc][0]), acc[es][0], 0, 0, 0);
                acc[es][1] = __builtin_amdgcn_mfma_f32_16x16x32_bf16(
                    a, __builtin_bit_cast(bf16x8, Bf[kc][1]), acc[es][1], 0, 0, 0);
            }
        }

        float v16[16];
        #pragma unroll
        for (int es = 0; es < 4; ++es)
            #pragma unroll
            for (int reg = 0; reg < 4; ++reg)
                v16[es * 4 + reg] = fmaxf(acc[es][0][reg] + b1v0, 0.f) * w2v0
                                  + fmaxf(acc[es][1][reg] + b1v1, 0.f) * w2v1;
        #pragma unroll
        for (int rnd = 0; rnd < 4; ++rnd) {
            const int o = 1 << rnd;
            const int hl = 8 >> rnd;
            #pragma unroll
            for (int i = 0; i < hl; ++i) {
                const float a = v16[i], b = v16[i + hl];
                const float s = (lane & o) ? a : b;
                const float r = __shfl_xor(s, o);
                v16[i] = ((lane & o) ? b : a) + r;
            }
        }
        {
            const int l4  = lane & 15;
            const int idx = ((l4 & 1) << 3) | ((l4 & 2) << 1) | ((l4 & 4) >> 1) | ((l4 & 8) >> 3);
            const int edge = (idx >> 2) * 16 + q * 4 + (idx & 3);
            part[w][edge] = v16[0];
        }
        __syncthreads();

        if (t < BM) {
            const int e = e0 + t;
            if (e < E) {
                const float s = part[0][t] + part[1][t] + part[2][t] + part[3][t] + b2v;
                out[e] = 1.f / (1.f + expf(-s));
            }
        }
    }
}

extern "C" void kernel_launch(void* const* d_in, const int* in_sizes, int n_in,
                              void* d_out, int out_size, void* d_ws, size_t ws_size,
                              hipStream_t stream) {
    const float* z  = (const float*)d_in[0];
    const void*  ei = d_in[1];
    const float* W1 = (const float*)d_in[2];
    const float* b1 = (const float*)d_in[3];
    const float* W2 = (const float*)d_in[4];
    const float* b2 = (const float*)d_in[5];
    float* out = (float*)d_out;
    int*   flag  = (int*)d_ws;
    uint4* wpack = (uint4*)((char*)d_ws + WPACK_OFF);
    char*  zbf   = (char*)d_ws + ZBF_OFF;

    const int E = in_sizes[1] / 2;
    const int use_ws  = (ws_size >= (size_t)(WPACK_OFF + WPACK_BYTES)) ? 1 : 0;
    const int use_zbf = (ws_size >= (size_t)(ZBF_OFF + ZBF_BYTES)) ? 1 : 0;

    hipLaunchKernelGGL(prep, dim3(1), dim3(256), 0, stream,
                       W1, (const unsigned*)ei, wpack, flag, use_ws);

    const int ntiles = (E + BM - 1) / BM;

    if (use_zbf) {
        const int n8 = NN * IN_DIM / 8;
        hipLaunchKernelGGL(zconv, dim3(4096), dim3(256), 0, stream,
                           (const float4*)z, (uint4*)zbf, n8);
        const int grid = (ntiles < GRID_BLOCKS) ? ntiles : GRID_BLOCKS;
        hipLaunchKernelGGL(lp_main_bf, dim3(grid), dim3(256), 0, stream,
                           zbf, (const int*)ei, b1, W2, b2, out, flag, wpack, E, ntiles);
    } else {
        const int grid = (ntiles < 768) ? ntiles : 768;
        hipLaunchKernelGGL(lp_main, dim3(grid), dim3(256), 0, stream,
                           z, (const int*)ei, W1, b1, W2, b2, out, flag, wpack,
                           use_ws, E, ntiles);
    }
}